// Round 4
// baseline (91.288 us; speedup 1.0000x reference)
//
#include <hip/hip_runtime.h>
#include <math.h>

#define BB 4
#define CC 64
#define HH 224
#define WW 224
#define HWW (HH*WW)
#define SS 257
#define CPB 8              // channels per pool block
#define NRC 8              // row chunks over the 222 interior rows
#define RPC 28             // interior rows per chunk (last chunk: 26)
#define ENCW (3*BB*CC*SS)  // 197376 key words

// Monotone float -> uint32 key (order-preserving), for integer atomicMax.
__device__ __forceinline__ unsigned fkey(float f) {
    unsigned u = __float_as_uint(f);
    return (u & 0x80000000u) ? ~u : (u | 0x80000000u);
}
__device__ __forceinline__ float funkey(unsigned k) {
    return (k & 0x80000000u) ? __uint_as_float(k & 0x7FFFFFFFu) : __uint_as_float(~k);
}
#define SENT 0x007FFFFFu  // fkey(-inf): empty-segment sentinel

// ---------------- init: enc keys -> SENT, nmax -> 0 ----------------
__global__ __launch_bounds__(256) void init_kernel(unsigned* __restrict__ enc,
                                                   int* __restrict__ nmax) {
    int i = blockIdx.x * 256 + threadIdx.x;
    if (i < ENCW / 4) ((uint4*)enc)[i] = make_uint4(SENT, SENT, SENT, SENT);
    if (i < 2 * BB) nmax[i] = 0;
}

// ---------------- segment-max pooling (+ folded nmax) ----------------
// grid (CPB-groups=8, row-chunks=8, z*4+b=12); block 256 (4 waves).
// Each block: 8 channels x one row-chunk. 1 label int4 + 8 feature float4
// loads per thread-iter = 9 independent 1KB wave-loads in flight (MLP fix),
// and label traffic drops 64x -> 8x (traffic fix). LDS read-check-atomic into
// partial [8][257] seg keys; merged to global enc keys via atomicMax.
__global__ __launch_bounds__(256) void pool_kernel(
    const float* __restrict__ fT, const float* __restrict__ fR,
    const float* __restrict__ fV,
    const int* __restrict__ labT, const int* __restrict__ labR,
    unsigned* __restrict__ enc, int* __restrict__ nmax)
{
    __shared__ unsigned seg[CPB * SS];
    __shared__ int wmax[4];
    const int cg = blockIdx.x, rc = blockIdx.y;
    const int z = blockIdx.z >> 2, b = blockIdx.z & 3;
    const float* src = (z == 0) ? fT : (z == 1) ? fR : fV;
    const int*   lab = (z == 0) ? labT : labR;

    for (int i = threadIdx.x; i < CPB * SS; i += 256) seg[i] = SENT;
    __syncthreads();

    const int h0 = rc * RPC;
    const int h1 = min(222, h0 + RPC);
    const int ngroups = (h1 - h0) * 56;        // 56 float4-groups per 224-wide row

    const int*    lp  = lab + (size_t)b * HWW;
    const int4*   lp4 = (const int4*)lp;
    const float4* fp4 = (const float4*)(src + (size_t)(b * CC + cg * CPB) * HWW);
    const int PS4 = HWW / 4;                   // plane stride in float4 units

    const bool do_nmax = (cg == 0) && (z < 2);
    int lmax = -1;

    for (int gi = threadIdx.x; gi < ngroups; gi += 256) {
        int h = gi / 56;
        int g = gi - h * 56;
        int idx4 = (h0 + h + 1) * 56 + g;      // image row = interior row + 1
        int4   l  = lp4[idx4];
        float4 f0 = fp4[idx4          ];
        float4 f1 = fp4[idx4 + 1 * PS4];
        float4 f2 = fp4[idx4 + 2 * PS4];
        float4 f3 = fp4[idx4 + 3 * PS4];
        float4 f4 = fp4[idx4 + 4 * PS4];
        float4 f5 = fp4[idx4 + 5 * PS4];
        float4 f6 = fp4[idx4 + 6 * PS4];
        float4 f7 = fp4[idx4 + 7 * PS4];
        if (do_nmax)
            lmax = max(lmax, max(max(l.x, l.y), max(l.z, l.w)));
        const bool mx = (g != 0), mw = (g != 55);   // border cols 0 / 223
#define PROC(F, CCN) do { \
        unsigned kx = fkey(F.x), ky = fkey(F.y), kz = fkey(F.z), kw = fkey(F.w); \
        unsigned* sg = seg + (CCN) * SS; \
        if (mx && kx > sg[l.x]) atomicMax(&sg[l.x], kx); \
        if (ky > sg[l.y]) atomicMax(&sg[l.y], ky); \
        if (kz > sg[l.z]) atomicMax(&sg[l.z], kz); \
        if (mw && kw > sg[l.w]) atomicMax(&sg[l.w], kw); } while (0)
        PROC(f0, 0); PROC(f1, 1); PROC(f2, 2); PROC(f3, 3);
        PROC(f4, 4); PROC(f5, 5); PROC(f6, 6); PROC(f7, 7);
#undef PROC
    }

    // nmax border rows (0 and 223) — interior loop covers rows 1..222 full width
    if (do_nmax && threadIdx.x < 56) {
        if (rc == 0) {
            int4 l = lp4[threadIdx.x];
            lmax = max(lmax, max(max(l.x, l.y), max(l.z, l.w)));
        }
        if (rc == NRC - 1) {
            int4 l = lp4[223 * 56 + threadIdx.x];
            lmax = max(lmax, max(max(l.x, l.y), max(l.z, l.w)));
        }
    }
    #pragma unroll
    for (int o = 32; o; o >>= 1) lmax = max(lmax, __shfl_xor(lmax, o, 64));
    if ((threadIdx.x & 63) == 0) wmax[threadIdx.x >> 6] = lmax;
    __syncthreads();   // also orders seg[] for the merge below
    if (do_nmax && threadIdx.x == 0) {
        int m = max(max(wmax[0], wmax[1]), max(wmax[2], wmax[3]));
        atomicMax(&nmax[z * BB + b], m + 1);
    }

    // merge partial seg keys -> global enc keys (layout matches: i = cc*SS + s)
    unsigned* gp = enc + (size_t)((z * BB + b) * CC + cg * CPB) * SS;
    for (int i = threadIdx.x; i < CPB * SS; i += 256) {
        unsigned k = seg[i];
        if (k != SENT) atomicMax(&gp[i], k);
    }
}

// ---------------- chan_norm + W@x + b -> q/k/v in [3][B][S][C] ----------------
// grid (ceil(S/8), B, 3); block 512 = 8 waves, one column per wave, lane = channel.
// Reads enc as keys; converts (fused finalize).
__global__ __launch_bounds__(512) void qkv_kernel(
    const unsigned* __restrict__ enc,
    const float* __restrict__ Wq, const float* __restrict__ bq,
    const float* __restrict__ Wk, const float* __restrict__ bk,
    const float* __restrict__ Wv, const float* __restrict__ bv,
    float* __restrict__ qkv)
{
    const int z = blockIdx.z, b = blockIdx.y;
    const int wid = threadIdx.x >> 6, lane = threadIdx.x & 63;
    const int n = blockIdx.x * 8 + wid;
    if (n >= SS) return;

    const float* Wm = (z == 0) ? Wq : (z == 1) ? Wk : Wv;
    const float* bm = (z == 0) ? bq : (z == 1) ? bk : bv;
    const unsigned* ep = enc + (size_t)((z * BB + b) * CC) * SS + n;

    unsigned kraw = ep[(size_t)lane * SS];
    float x = (kraw == SENT) ? 0.0f : funkey(kraw);   // empty segments -> 0
    if (z != 2) {  // chan_norm for q,k inputs
        float s = x;
        for (int o = 32; o; o >>= 1) s += __shfl_xor(s, o, 64);
        float xm = x - s * (1.0f / 64.0f);
        float s2 = xm * xm;
        for (int o = 32; o; o >>= 1) s2 += __shfl_xor(s2, o, 64);
        x = xm / (sqrtf(s2) + 1e-5f);
    }
    float acc = bm[lane];
    #pragma unroll
    for (int cI = 0; cI < 64; ++cI) {
        float xc = __shfl(x, cI, 64);
        acc = fmaf(Wm[lane * 64 + cI], xc, acc);
    }
    qkv[(size_t)((z * BB + b) * SS + n) * CC + lane] = acc;
}

// ---------------- attention row + PV ----------------
// grid (S, B); block 256. One (b, n) row per block.
__global__ __launch_bounds__(256) void attn_kernel(
    const float* __restrict__ qkv, const int* __restrict__ nmax,
    float* __restrict__ wg)
{
    const int n = blockIdx.x, b = blockIdx.y, t = threadIdx.x;
    __shared__ float qs[CC];
    __shared__ float sim[512];
    __shared__ float red[256];
    __shared__ float pv[4][64];

    const int nT = nmax[b], nR = nmax[BB + b];
    float* wp = wg + (size_t)(b * SS + n) * CC;
    if (n >= nT) {                       // tmask zeroes this row
        if (t < CC) wp[t] = 0.0f;
        return;
    }
    const float* q = qkv + (size_t)(0 * BB + b) * SS * CC;
    const float* k = qkv + (size_t)(1 * BB + b) * SS * CC;
    const float* v = qkv + (size_t)(2 * BB + b) * SS * CC;

    if (t < CC) qs[t] = q[(size_t)n * CC + t];
    sim[t] = -INFINITY;
    sim[t + 256] = -INFINITY;
    __syncthreads();

    for (int m = t; m < SS; m += 256) {
        float s = -INFINITY;
        if (m < nR) {
            const float4* kr = (const float4*)(k + (size_t)m * CC);
            float acc = 0.0f;
            #pragma unroll
            for (int i = 0; i < 16; ++i) {
                float4 kv = kr[i];
                acc += qs[4*i+0]*kv.x + qs[4*i+1]*kv.y + qs[4*i+2]*kv.z + qs[4*i+3]*kv.w;
            }
            s = acc * 100.0f;            // /0.01 temperature
        }
        sim[m] = s;
    }
    __syncthreads();

    red[t] = fmaxf(sim[t], sim[t + 256]);
    __syncthreads();
    for (int s = 128; s > 0; s >>= 1) {
        if (t < s) red[t] = fmaxf(red[t], red[t + s]);
        __syncthreads();
    }
    const float mx = red[0];
    __syncthreads();

    float psum = 0.0f;
    for (int m = t; m < SS; m += 256) {
        float e = expf(sim[m] - mx);     // exp(-inf - mx) = 0 for masked cols
        sim[m] = e;
        psum += e;
    }
    red[t] = psum;
    __syncthreads();
    for (int s = 128; s > 0; s >>= 1) {
        if (t < s) red[t] += red[t + s];
        __syncthreads();
    }
    const float rdenom = 1.0f / red[0];

    const int g = t >> 6, c = t & 63;
    float acc = 0.0f;
    for (int m = g; m < SS; m += 4)
        acc = fmaf(sim[m], v[(size_t)m * CC + c], acc);
    pv[g][c] = acc;
    __syncthreads();
    if (t < CC)
        wp[t] = (pv[0][t] + pv[1][t] + pv[2][t] + pv[3][t]) * rdenom;
}

// ---------------- unpool gather ----------------
__global__ __launch_bounds__(256) void unpool_kernel(
    const float* __restrict__ wg, const int* __restrict__ labT,
    float* __restrict__ out)
{
    const int idx = blockIdx.x * 256 + threadIdx.x;  // over B*HW
    if (idx >= BB * HWW) return;
    const int b = idx / HWW, hw = idx - b * HWW;
    const int l = labT[idx];
    const float4* row = (const float4*)(wg + (size_t)(b * SS + l) * CC);
    float* op = out + (size_t)b * CC * HWW + hw;
    #pragma unroll
    for (int i = 0; i < 16; ++i) {
        float4 r = row[i];
        op[(size_t)(4*i+0) * HWW] = r.x;
        op[(size_t)(4*i+1) * HWW] = r.y;
        op[(size_t)(4*i+2) * HWW] = r.z;
        op[(size_t)(4*i+3) * HWW] = r.w;
    }
}

extern "C" void kernel_launch(void* const* d_in, const int* in_sizes, int n_in,
                              void* d_out, int out_size, void* d_ws, size_t ws_size,
                              hipStream_t stream) {
    (void)in_sizes; (void)n_in; (void)out_size; (void)ws_size;
    const float* fT  = (const float*)d_in[0];
    const float* fR  = (const float*)d_in[1];
    const float* fV  = (const float*)d_in[2];
    const float* Wq  = (const float*)d_in[3];
    const float* bq  = (const float*)d_in[4];
    const float* Wk  = (const float*)d_in[5];
    const float* bk  = (const float*)d_in[6];
    const float* Wv  = (const float*)d_in[7];
    const float* bv  = (const float*)d_in[8];
    const int* labT  = (const int*)d_in[9];
    const int* labR  = (const int*)d_in[10];
    float* out = (float*)d_out;

    unsigned* enc = (unsigned*)d_ws;              // [3][B][C][S] as keys
    float* qkv  = (float*)d_ws + ENCW;            // [3][B][S][C]
    float* wg   = qkv + 3 * BB * CC * SS;         // [B][S][C]
    int*   nmax = (int*)(wg + BB * CC * SS);      // [2][B]

    init_kernel<<<(ENCW / 4 + 255) / 256, 256, 0, stream>>>(enc, nmax);
    pool_kernel<<<dim3(CPB, NRC, 12), 256, 0, stream>>>(fT, fR, fV, labT, labR, enc, nmax);
    qkv_kernel<<<dim3((SS + 7) / 8, BB, 3), 512, 0, stream>>>(enc, Wq, bq, Wk, bk, Wv, bv, qkv);
    attn_kernel<<<dim3(SS, BB), 256, 0, stream>>>(qkv, nmax, wg);
    unpool_kernel<<<(BB * HWW + 255) / 256, 256, 0, stream>>>(wg, labT, out);
}